// Round 1
// baseline (2458.836 us; speedup 1.0000x reference)
//
#include <hip/hip_runtime.h>
#include <hip/hip_bf16.h>

// ---------------------------------------------------------------------------
// DRSAR_FL_RNN: B=512, T=128, F=256, H=512, K=3
// out = concat(logits[512], weights[256]) fp32
//
// Pipeline:
//   prep:  weights=sigmoid(theta); WxT/WhT bf16 transposed (N-major) for MFMA
//          B-fragments; gating constants packed [H][12].
//   gemm1: xw = bf16(x*weights) @ bf16(Wx), fp32 acc, stored bf16 [65536,512].
//   scan:  32 WGs x 16 batch rows; 128 steps; h@Wh via mfma 16x16x32 bf16 with
//          B-frags streamed from L2 (WhT), h in fp32 regs + bf16 LDS mirror.
// ---------------------------------------------------------------------------

#define B_  512
#define T_  128
#define F_  256
#define H_  512

#define LOG2E 1.4426950408889634f

typedef __attribute__((ext_vector_type(8))) short short8;
typedef __attribute__((ext_vector_type(4))) float float4v;

__device__ inline ushort f2bf(float f) {
  __hip_bfloat16 h = __float2bfloat16(f);
  return *reinterpret_cast<ushort*>(&h);
}
__device__ inline float bf2f(ushort u) {
  unsigned v = ((unsigned)u) << 16;
  return __uint_as_float(v);
}
__device__ inline float fexp2(float x) {
#if __has_builtin(__builtin_amdgcn_exp2f)
  return __builtin_amdgcn_exp2f(x);
#else
  return exp2f(x);
#endif
}
__device__ inline float frcp(float x) {
#if __has_builtin(__builtin_amdgcn_rcpf)
  return __builtin_amdgcn_rcpf(x);
#else
  return 1.0f / x;
#endif
}

// ws layout (bytes):
//   xw  bf16 [65536][512] : 0          .. 67108864
//   WxT bf16 [512][256]   : 67108864   .. 67371008
//   WhT bf16 [512][512]   : 67371008   .. 67895296
//   gp  f32  [512][12]    : 67895296   .. 67919872   {c,a,q}x3, b, Wc, pad
//   wts f32  [256]        : 67919872   .. 67920896
#define WS_WXT 67108864
#define WS_WHT 67371008
#define WS_GP  67895296
#define WS_WTS 67919872

__global__ void prep_kernel(const float* __restrict__ theta,
                            const float* __restrict__ Wx,
                            const float* __restrict__ Wh,
                            const float* __restrict__ b,
                            const float* __restrict__ c,
                            const float* __restrict__ sigma,
                            const float* __restrict__ q,
                            const float* __restrict__ Wc,
                            float* __restrict__ out_w,
                            ushort* __restrict__ WxT,
                            ushort* __restrict__ WhT,
                            float* __restrict__ gp,
                            float* __restrict__ wts) {
  const int i = blockIdx.x * 256 + threadIdx.x;  // grid covers 262144
  if (i < F_) {
    float w = 1.f / (1.f + __expf(-theta[i]));
    out_w[i] = w;
    wts[i] = w;
  }
  if (i < H_ * F_) {                       // WxT[n][f] = Wx[f][n]
    int n = i >> 8, f = i & 255;
    WxT[i] = f2bf(Wx[f * H_ + n]);
  }
  {                                        // WhT[n][j] = Wh[j][n]
    int n = i >> 9, j = i & 511;
    WhT[i] = f2bf(Wh[j * H_ + n]);
  }
  if (i < H_) {
#pragma unroll
    for (int k = 0; k < 3; ++k) {
      float s = sigma[i * 3 + k];
      float inv = 1.f / (2.f * s * s + 1e-8f);
      gp[i * 12 + k * 3 + 0] = c[i * 3 + k];
      gp[i * 12 + k * 3 + 1] = -LOG2E * inv;   // mu = exp2(d*d*a)
      gp[i * 12 + k * 3 + 2] = q[i * 3 + k];
    }
    gp[i * 12 + 9]  = b[i];
    gp[i * 12 + 10] = Wc[i];
    gp[i * 12 + 11] = 0.f;
  }
}

// xw[m][n] = sum_f bf16(x[m][f]*w[f]) * bf16(Wx[f][n]); grid (1024, 2), 256 thr
__global__ __launch_bounds__(256, 1) void gemm1_kernel(
    const float* __restrict__ x, const float* __restrict__ wts,
    const ushort* __restrict__ WxT, ushort* __restrict__ xw) {
  __shared__ ushort A[64 * 264];  // 64 rows x 256 (+8 pad) bf16
  const int tid = threadIdx.x;
  const int lane = tid & 63, wave = tid >> 6;
  const int col16 = lane & 15, quad = lane >> 4;
  const int m0 = blockIdx.x * 64;
  const int n0 = blockIdx.y * 256;

  {  // stage A-tile: xf = x*weights -> bf16
    const int r = tid >> 2, f0 = (tid & 3) * 64;
    const float4* xp = (const float4*)(x + (size_t)(m0 + r) * F_ + f0);
    const float4* wp = (const float4*)(wts + f0);
#pragma unroll
    for (int j = 0; j < 16; ++j) {
      float4 xv = xp[j];
      float4 wv = wp[j];
      ushort4 o;
      o.x = f2bf(xv.x * wv.x);
      o.y = f2bf(xv.y * wv.y);
      o.z = f2bf(xv.z * wv.z);
      o.w = f2bf(xv.w * wv.w);
      *(ushort4*)&A[r * 264 + f0 + j * 4] = o;
    }
  }
  __syncthreads();

  float4v acc[16];
  const float4v zero = {0.f, 0.f, 0.f, 0.f};
#pragma unroll
  for (int i = 0; i < 16; ++i) acc[i] = zero;

#pragma unroll
  for (int kt = 0; kt < 8; ++kt) {  // K=256 = 8 x 32
    short8 af = *(const short8*)&A[(wave * 16 + col16) * 264 + kt * 32 + quad * 8];
#pragma unroll
    for (int nt = 0; nt < 16; ++nt) {
      const int n = n0 + nt * 16 + col16;
      short8 bf = *(const short8*)(WxT + n * F_ + kt * 32 + quad * 8);
      acc[nt] = __builtin_amdgcn_mfma_f32_16x16x32_bf16(af, bf, acc[nt], 0, 0, 0);
    }
  }
  const int row_base = m0 + wave * 16 + quad * 4;
#pragma unroll
  for (int nt = 0; nt < 16; ++nt) {
    const int col = n0 + nt * 16 + col16;
#pragma unroll
    for (int rg = 0; rg < 4; ++rg)
      xw[(size_t)(row_base + rg) * H_ + col] = f2bf(acc[nt][rg]);
  }
}

// 32 WGs x 256 thr; WG owns 16 batch rows; wave owns 128 h-columns (8 n-tiles)
__global__ __launch_bounds__(256, 1) void scan_kernel(
    const ushort* __restrict__ xw, const ushort* __restrict__ WhT,
    const float* __restrict__ gp, const float* __restrict__ bc,
    float* __restrict__ out) {
  __shared__ ushort hl[16 * 520];       // h mirror bf16, padded rows
  __shared__ float gpl[512 * 12];       // gating constants
  __shared__ float red[4][16];
  const int tid = threadIdx.x;
  const int lane = tid & 63, wave = tid >> 6;
  const int col16 = lane & 15, quad = lane >> 4;
  const int b0 = blockIdx.x * 16;
  const int rowb = quad * 4;

  for (int i = tid; i < 16 * 520; i += 256) hl[i] = 0;
  for (int i = tid; i < 512 * 12 / 4; i += 256)
    ((float4*)gpl)[i] = ((const float4*)gp)[i];
  __syncthreads();

  int cols[8];
  float bcol[8];
#pragma unroll
  for (int nt = 0; nt < 8; ++nt) {
    cols[nt] = (wave * 8 + nt) * 16 + col16;
    bcol[nt] = gpl[cols[nt] * 12 + 9];
  }
  float hreg[8][4];
#pragma unroll
  for (int nt = 0; nt < 8; ++nt)
#pragma unroll
    for (int rg = 0; rg < 4; ++rg) hreg[nt][rg] = 0.f;

#pragma clang loop unroll(disable)
  for (int t = 0; t < T_; ++t) {
    float4v acc[8];
    float nw[8][4];
    // z init = xw + b; stash new_info = tanh(xw)
#pragma unroll
    for (int nt = 0; nt < 8; ++nt) {
#pragma unroll
      for (int rg = 0; rg < 4; ++rg) {
        float v = bf2f(xw[(size_t)((b0 + rowb + rg) * T_ + t) * H_ + cols[nt]]);
        acc[nt][rg] = v + bcol[nt];
        float e = fexp2(v * (2.f * LOG2E));          // exp(2v)
        nw[nt][rg] = 1.f - 2.f * frcp(1.f + e);      // tanh(v)
      }
    }
    // z += h @ Wh  (A-frag: h from LDS; B-frag: WhT streamed from L2)
#pragma unroll 4
    for (int kt = 0; kt < 16; ++kt) {
      short8 af = *(const short8*)&hl[col16 * 520 + kt * 32 + quad * 8];
      const ushort* bp = WhT + kt * 32 + quad * 8 + col16 * H_;
#pragma unroll
      for (int nt = 0; nt < 8; ++nt) {
        short8 bf = *(const short8*)(bp + (wave * 8 + nt) * (16 * H_));
        acc[nt] = __builtin_amdgcn_mfma_f32_16x16x32_bf16(af, bf, acc[nt], 0, 0, 0);
      }
    }
    // fuzzy gating + h update (registers only)
#pragma unroll
    for (int nt = 0; nt < 8; ++nt) {
      const float* g = &gpl[cols[nt] * 12];
      float c0 = g[0], a0 = g[1], q0 = g[2];
      float c1 = g[3], a1 = g[4], q1 = g[5];
      float c2 = g[6], a2 = g[7], q2 = g[8];
#pragma unroll
      for (int rg = 0; rg < 4; ++rg) {
        float z = acc[nt][rg];
        float d0 = z - c0, d1 = z - c1, d2 = z - c2;
        float m0 = fexp2(d0 * d0 * a0);
        float m1 = fexp2(d1 * d1 * a1);
        float m2 = fexp2(d2 * d2 * a2);
        float num = m0 * q0 + m1 * q1 + m2 * q2;
        float den = m0 + m1 + m2 + 1e-8f;
        float s = num * frcp(den);
        float gg = frcp(1.f + fexp2(-s * LOG2E));    // sigmoid(s)
        hreg[nt][rg] += gg * (nw[nt][rg] - hreg[nt][rg]);
      }
    }
    __syncthreads();  // all waves done reading hl for this step
#pragma unroll
    for (int nt = 0; nt < 8; ++nt)
#pragma unroll
      for (int rg = 0; rg < 4; ++rg)
        hl[(rowb + rg) * 520 + cols[nt]] = f2bf(hreg[nt][rg]);
    __syncthreads();  // hl updated before next step's A-frag reads
  }

  // logits[b] = sum_h h[b][h]*Wc[h] + bc
  float part[4] = {0.f, 0.f, 0.f, 0.f};
#pragma unroll
  for (int nt = 0; nt < 8; ++nt) {
    float wc = gpl[cols[nt] * 12 + 10];
#pragma unroll
    for (int rg = 0; rg < 4; ++rg) part[rg] += hreg[nt][rg] * wc;
  }
#pragma unroll
  for (int rg = 0; rg < 4; ++rg) {
#pragma unroll
    for (int m = 1; m < 16; m <<= 1) part[rg] += __shfl_xor(part[rg], m, 64);
    if (col16 == 0) red[wave][rowb + rg] = part[rg];
  }
  __syncthreads();
  if (tid < 16)
    out[b0 + tid] = red[0][tid] + red[1][tid] + red[2][tid] + red[3][tid] + bc[0];
}

extern "C" void kernel_launch(void* const* d_in, const int* in_sizes, int n_in,
                              void* d_out, int out_size, void* d_ws, size_t ws_size,
                              hipStream_t stream) {
  const float* x     = (const float*)d_in[0];
  const float* theta = (const float*)d_in[1];
  const float* Wx    = (const float*)d_in[2];
  const float* Wh    = (const float*)d_in[3];
  const float* b     = (const float*)d_in[4];
  const float* c     = (const float*)d_in[5];
  const float* sigma = (const float*)d_in[6];
  const float* q     = (const float*)d_in[7];
  const float* Wc    = (const float*)d_in[8];
  const float* bc    = (const float*)d_in[9];
  float* out = (float*)d_out;

  ushort* xw  = (ushort*)d_ws;
  ushort* WxT = (ushort*)((char*)d_ws + WS_WXT);
  ushort* WhT = (ushort*)((char*)d_ws + WS_WHT);
  float*  gp  = (float*)((char*)d_ws + WS_GP);
  float*  wts = (float*)((char*)d_ws + WS_WTS);

  hipLaunchKernelGGL(prep_kernel, dim3(1024), dim3(256), 0, stream,
                     theta, Wx, Wh, b, c, sigma, q, Wc, out + B_, WxT, WhT, gp, wts);
  hipLaunchKernelGGL(gemm1_kernel, dim3(1024, 2), dim3(256), 0, stream,
                     x, wts, WxT, xw);
  hipLaunchKernelGGL(scan_kernel, dim3(32), dim3(256), 0, stream,
                     xw, WhT, gp, bc, out);
}

// Round 2
// 2334.350 us; speedup vs baseline: 1.0533x; 1.0533x over previous
//
#include <hip/hip_runtime.h>
#include <hip/hip_bf16.h>

// ---------------------------------------------------------------------------
// DRSAR_FL_RNN: B=512, T=128, F=256, H=512, K=3
// out = concat(logits[512], weights[256]) fp32
//
// R2: scan WG grown to 1024 threads (16 waves/CU) so the WhT L2 stream has
// 16 waves of latency hiding instead of 4. xw stored [T][B][H] so each step
// reads one contiguous 16KB slab per WG.
// ---------------------------------------------------------------------------

#define B_  512
#define T_  128
#define F_  256
#define H_  512

#define LOG2E 1.4426950408889634f

typedef __attribute__((ext_vector_type(8))) short short8;
typedef __attribute__((ext_vector_type(4))) float float4v;

__device__ inline ushort f2bf(float f) {
  __hip_bfloat16 h = __float2bfloat16(f);
  return *reinterpret_cast<ushort*>(&h);
}
__device__ inline float bf2f(ushort u) {
  unsigned v = ((unsigned)u) << 16;
  return __uint_as_float(v);
}
__device__ inline float fexp2(float x) {
#if __has_builtin(__builtin_amdgcn_exp2f)
  return __builtin_amdgcn_exp2f(x);
#else
  return exp2f(x);
#endif
}
__device__ inline float frcp(float x) {
#if __has_builtin(__builtin_amdgcn_rcpf)
  return __builtin_amdgcn_rcpf(x);
#else
  return 1.0f / x;
#endif
}

// ws layout (bytes):
//   xw  bf16 [T][B][H]    : 0          .. 67108864   (transposed: step-major)
//   WxT bf16 [512][256]   : 67108864   .. 67371008
//   WhT bf16 [512][512]   : 67371008   .. 67895296
//   gp  f32  [512][12]    : 67895296   .. 67919872   {c,a,q}x3, b, Wc, pad
//   wts f32  [256]        : 67919872   .. 67920896
#define WS_WXT 67108864
#define WS_WHT 67371008
#define WS_GP  67895296
#define WS_WTS 67919872

__global__ void prep_kernel(const float* __restrict__ theta,
                            const float* __restrict__ Wx,
                            const float* __restrict__ Wh,
                            const float* __restrict__ b,
                            const float* __restrict__ c,
                            const float* __restrict__ sigma,
                            const float* __restrict__ q,
                            const float* __restrict__ Wc,
                            float* __restrict__ out_w,
                            ushort* __restrict__ WxT,
                            ushort* __restrict__ WhT,
                            float* __restrict__ gp,
                            float* __restrict__ wts) {
  const int i = blockIdx.x * 256 + threadIdx.x;  // grid covers 262144
  if (i < F_) {
    float w = 1.f / (1.f + __expf(-theta[i]));
    out_w[i] = w;
    wts[i] = w;
  }
  if (i < H_ * F_) {                       // WxT[n][f] = Wx[f][n]
    int n = i >> 8, f = i & 255;
    WxT[i] = f2bf(Wx[f * H_ + n]);
  }
  {                                        // WhT[n][j] = Wh[j][n]
    int n = i >> 9, j = i & 511;
    WhT[i] = f2bf(Wh[j * H_ + n]);
  }
  if (i < H_) {
#pragma unroll
    for (int k = 0; k < 3; ++k) {
      float s = sigma[i * 3 + k];
      float inv = 1.f / (2.f * s * s + 1e-8f);
      gp[i * 12 + k * 3 + 0] = c[i * 3 + k];
      gp[i * 12 + k * 3 + 1] = -LOG2E * inv;   // mu = exp2(d*d*a)
      gp[i * 12 + k * 3 + 2] = q[i * 3 + k];
    }
    gp[i * 12 + 9]  = b[i];
    gp[i * 12 + 10] = Wc[i];
    gp[i * 12 + 11] = 0.f;
  }
}

// xw[t][b][n] = sum_f bf16(x[b][t][f]*w[f]) * bf16(Wx[f][n]); grid (1024,2)
__global__ __launch_bounds__(256, 1) void gemm1_kernel(
    const float* __restrict__ x, const float* __restrict__ wts,
    const ushort* __restrict__ WxT, ushort* __restrict__ xw) {
  __shared__ ushort A[64 * 264];  // 64 rows x 256 (+8 pad) bf16
  const int tid = threadIdx.x;
  const int lane = tid & 63, wave = tid >> 6;
  const int col16 = lane & 15, quad = lane >> 4;
  const int m0 = blockIdx.x * 64;
  const int n0 = blockIdx.y * 256;

  {  // stage A-tile: xf = x*weights -> bf16
    const int r = tid >> 2, f0 = (tid & 3) * 64;
    const float4* xp = (const float4*)(x + (size_t)(m0 + r) * F_ + f0);
    const float4* wp = (const float4*)(wts + f0);
#pragma unroll
    for (int j = 0; j < 16; ++j) {
      float4 xv = xp[j];
      float4 wv = wp[j];
      ushort4 o;
      o.x = f2bf(xv.x * wv.x);
      o.y = f2bf(xv.y * wv.y);
      o.z = f2bf(xv.z * wv.z);
      o.w = f2bf(xv.w * wv.w);
      *(ushort4*)&A[r * 264 + f0 + j * 4] = o;
    }
  }
  __syncthreads();

  float4v acc[16];
  const float4v zero = {0.f, 0.f, 0.f, 0.f};
#pragma unroll
  for (int i = 0; i < 16; ++i) acc[i] = zero;

#pragma unroll
  for (int kt = 0; kt < 8; ++kt) {  // K=256 = 8 x 32
    short8 af = *(const short8*)&A[(wave * 16 + col16) * 264 + kt * 32 + quad * 8];
#pragma unroll
    for (int nt = 0; nt < 16; ++nt) {
      const int n = n0 + nt * 16 + col16;
      short8 bf = *(const short8*)(WxT + n * F_ + kt * 32 + quad * 8);
      acc[nt] = __builtin_amdgcn_mfma_f32_16x16x32_bf16(af, bf, acc[nt], 0, 0, 0);
    }
  }
  const int row_base = m0 + wave * 16 + quad * 4;
#pragma unroll
  for (int nt = 0; nt < 16; ++nt) {
    const int col = n0 + nt * 16 + col16;
#pragma unroll
    for (int rg = 0; rg < 4; ++rg) {
      const int row = row_base + rg;          // row = b*T + t
      const int bb = row >> 7;                // / T_
      const int tt = row & 127;               // % T_
      xw[((size_t)tt * B_ + bb) * H_ + col] = f2bf(acc[nt][rg]);
    }
  }
}

// 32 WGs x 1024 thr (16 waves); WG owns 16 batch rows; wave owns 32 h-cols.
__global__ __launch_bounds__(1024) void scan_kernel(
    const ushort* __restrict__ xw, const ushort* __restrict__ WhT,
    const float* __restrict__ gp, const float* __restrict__ bc,
    float* __restrict__ out) {
  __shared__ ushort hl[16 * 520];       // h mirror bf16, padded rows
  __shared__ float gpl[512 * 12];       // gating constants
  __shared__ float red[16][16];
  const int tid = threadIdx.x;
  const int lane = tid & 63, wave = tid >> 6;
  const int col16 = lane & 15, quad = lane >> 4;
  const int b0 = blockIdx.x * 16;
  const int rowb = quad * 4;

  for (int i = tid; i < 16 * 520; i += 1024) hl[i] = 0;
  for (int i = tid; i < 512 * 12 / 4; i += 1024)
    ((float4*)gpl)[i] = ((const float4*)gp)[i];
  __syncthreads();

  int cols[2];
  float bcol[2];
  const ushort* bptr[2];
#pragma unroll
  for (int nt = 0; nt < 2; ++nt) {
    cols[nt] = wave * 32 + nt * 16 + col16;
    bcol[nt] = gpl[cols[nt] * 12 + 9];
    bptr[nt] = WhT + (size_t)cols[nt] * H_;
  }
  // gating constants resident in registers (18 VGPRs)
  float gc[2][9];
#pragma unroll
  for (int nt = 0; nt < 2; ++nt)
#pragma unroll
    for (int j = 0; j < 9; ++j) gc[nt][j] = gpl[cols[nt] * 12 + j];

  float hreg[2][4];
#pragma unroll
  for (int nt = 0; nt < 2; ++nt)
#pragma unroll
    for (int rg = 0; rg < 4; ++rg) hreg[nt][rg] = 0.f;

#pragma clang loop unroll(disable)
  for (int t = 0; t < T_; ++t) {
    float4v acc[2];
    float nw[2][4];
    // z init = xw + b; stash new_info = tanh(xw). xw slab [t][b0..b0+16][H]
    const ushort* xwt = xw + (size_t)t * (B_ * H_);
#pragma unroll
    for (int nt = 0; nt < 2; ++nt) {
#pragma unroll
      for (int rg = 0; rg < 4; ++rg) {
        float v = bf2f(xwt[(size_t)(b0 + rowb + rg) * H_ + cols[nt]]);
        acc[nt][rg] = v + bcol[nt];
        float e = fexp2(v * (2.f * LOG2E));          // exp(2v)
        nw[nt][rg] = 1.f - 2.f * frcp(1.f + e);      // tanh(v)
      }
    }
    // z += h @ Wh  (A-frag: h from LDS; B-frag: WhT streamed from L2)
#pragma unroll 4
    for (int kt = 0; kt < 16; ++kt) {
      short8 af = *(const short8*)&hl[col16 * 520 + kt * 32 + quad * 8];
      const int ko = kt * 32 + quad * 8;
#pragma unroll
      for (int nt = 0; nt < 2; ++nt) {
        short8 bf = *(const short8*)(bptr[nt] + ko);
        acc[nt] = __builtin_amdgcn_mfma_f32_16x16x32_bf16(af, bf, acc[nt], 0, 0, 0);
      }
    }
    // fuzzy gating + h update (registers only)
#pragma unroll
    for (int nt = 0; nt < 2; ++nt) {
      const float* g = gc[nt];
#pragma unroll
      for (int rg = 0; rg < 4; ++rg) {
        float z = acc[nt][rg];
        float d0 = z - g[0], d1 = z - g[3], d2 = z - g[6];
        float m0 = fexp2(d0 * d0 * g[1]);
        float m1 = fexp2(d1 * d1 * g[4]);
        float m2 = fexp2(d2 * d2 * g[7]);
        float num = m0 * g[2] + m1 * g[5] + m2 * g[8];
        float den = m0 + m1 + m2 + 1e-8f;
        float s = num * frcp(den);
        float gg = frcp(1.f + fexp2(-s * LOG2E));    // sigmoid(s)
        hreg[nt][rg] += gg * (nw[nt][rg] - hreg[nt][rg]);
      }
    }
    __syncthreads();  // all waves done reading hl for this step
#pragma unroll
    for (int nt = 0; nt < 2; ++nt)
#pragma unroll
      for (int rg = 0; rg < 4; ++rg)
        hl[(rowb + rg) * 520 + cols[nt]] = f2bf(hreg[nt][rg]);
    __syncthreads();  // hl updated before next step's A-frag reads
  }

  // logits[b] = sum_h h[b][h]*Wc[h] + bc
  float part[4] = {0.f, 0.f, 0.f, 0.f};
#pragma unroll
  for (int nt = 0; nt < 2; ++nt) {
    float wc = gpl[cols[nt] * 12 + 10];
#pragma unroll
    for (int rg = 0; rg < 4; ++rg) part[rg] += hreg[nt][rg] * wc;
  }
#pragma unroll
  for (int rg = 0; rg < 4; ++rg) {
#pragma unroll
    for (int m = 1; m < 16; m <<= 1) part[rg] += __shfl_xor(part[rg], m, 64);
    if (col16 == 0) red[wave][rowb + rg] = part[rg];
  }
  __syncthreads();
  if (tid < 16) {
    float s = bc[0];
#pragma unroll
    for (int w = 0; w < 16; ++w) s += red[w][tid];
    out[b0 + tid] = s;
  }
}

extern "C" void kernel_launch(void* const* d_in, const int* in_sizes, int n_in,
                              void* d_out, int out_size, void* d_ws, size_t ws_size,
                              hipStream_t stream) {
  const float* x     = (const float*)d_in[0];
  const float* theta = (const float*)d_in[1];
  const float* Wx    = (const float*)d_in[2];
  const float* Wh    = (const float*)d_in[3];
  const float* b     = (const float*)d_in[4];
  const float* c     = (const float*)d_in[5];
  const float* sigma = (const float*)d_in[6];
  const float* q     = (const float*)d_in[7];
  const float* Wc    = (const float*)d_in[8];
  const float* bc    = (const float*)d_in[9];
  float* out = (float*)d_out;

  ushort* xw  = (ushort*)d_ws;
  ushort* WxT = (ushort*)((char*)d_ws + WS_WXT);
  ushort* WhT = (ushort*)((char*)d_ws + WS_WHT);
  float*  gp  = (float*)((char*)d_ws + WS_GP);
  float*  wts = (float*)((char*)d_ws + WS_WTS);

  hipLaunchKernelGGL(prep_kernel, dim3(1024), dim3(256), 0, stream,
                     theta, Wx, Wh, b, c, sigma, q, Wc, out + B_, WxT, WhT, gp, wts);
  hipLaunchKernelGGL(gemm1_kernel, dim3(1024, 2), dim3(256), 0, stream,
                     x, wts, WxT, xw);
  hipLaunchKernelGGL(scan_kernel, dim3(32), dim3(1024), 0, stream,
                     xw, WhT, gp, bc, out);
}

// Round 3
// 629.025 us; speedup vs baseline: 3.9090x; 3.7111x over previous
//
#include <hip/hip_runtime.h>
#include <hip/hip_bf16.h>

// ---------------------------------------------------------------------------
// DRSAR_FL_RNN: B=512, T=128, F=256, H=512, K=3
// R3: weight-stationary scan. Wh quantized to i8 (per-column scales) and held
// ENTIRELY in VGPRs (128/lane, 8 waves/CU); h carried fp32 in regs, mirrored
// as i8 in an 8KB LDS buffer for MFMA A-frags (mfma_i32_16x16x64_i8).
// Zero per-step global weight traffic. All global arrays fragment-linear.
// ---------------------------------------------------------------------------

#define B_  512
#define T_  128
#define F_  256
#define H_  512
#define LOG2E 1.4426950408889634f

typedef __attribute__((ext_vector_type(8))) short short8;
typedef __attribute__((ext_vector_type(4))) float float4v;
typedef __attribute__((ext_vector_type(4))) int int4i;

__device__ inline ushort f2bf(float f) {
  __hip_bfloat16 h = __float2bfloat16(f);
  return *reinterpret_cast<ushort*>(&h);
}
__device__ inline float bf2f(unsigned u) {
  return __uint_as_float(u << 16);
}
__device__ inline float fexp2(float x) {
#if __has_builtin(__builtin_amdgcn_exp2f)
  return __builtin_amdgcn_exp2f(x);
#else
  return exp2f(x);
#endif
}
__device__ inline float frcp(float x) {
#if __has_builtin(__builtin_amdgcn_rcpf)
  return __builtin_amdgcn_rcpf(x);
#else
  return 1.0f / x;
#endif
}

// ws layout (bytes):
//   xw2  bf16 frag-linear [T][32 blk][8 w][4 nt][64 lane][4 rg] : 0 .. 67108864
//   W2I8 i8 frag-linear [8 kt][32 nb][64 lane][16 B]   : 67108864 (262144)
//   WXF  bf16 frag-linear [8 kt][32 nb][64 lane][8]    : 67371008 (262144)
//   GP8  f32 [512][8] {c0,c1,c2,a0,a1,a2,qpk01,qpk2}   : 67633152 (16384)
//   BVEC f32 [512]                                     : 67649536
//   WCV  f32 [512]                                     : 67651584
//   SCOL f32 [512]  (colmax/(127*127))                 : 67653632
//   INVS f32 [512]  (127/colmax)                       : 67655680
//   WTS  f32 [256]                                     : 67657728
#define WS_W2I8 67108864
#define WS_WXF  67371008
#define WS_GP8  67633152
#define WS_BVEC 67649536
#define WS_WCV  67651584
#define WS_SCOL 67653632
#define WS_INVS 67655680
#define WS_WTS  67657728

__global__ void prep_misc(const float* __restrict__ theta,
                          const float* __restrict__ Wx,
                          const float* __restrict__ b,
                          const float* __restrict__ c,
                          const float* __restrict__ sigma,
                          const float* __restrict__ q,
                          const float* __restrict__ Wc,
                          float* __restrict__ out_w,
                          ushort* __restrict__ WxF,
                          float* __restrict__ gp8,
                          float* __restrict__ bvec,
                          float* __restrict__ wcv,
                          float* __restrict__ wts) {
  const int i = blockIdx.x * 256 + threadIdx.x;  // 512 blocks -> 131072
  if (i < F_) {
    float w = 1.f / (1.f + __expf(-theta[i]));
    out_w[i] = w;
    wts[i] = w;
  }
  {  // WxF[((kt*32+nb)*64+lane)*8 + j] = bf16(Wx[f][n])
    const int j = i & 7, lane = (i >> 3) & 63, nbkt = i >> 9;
    const int nb = nbkt & 31, kt = nbkt >> 5;
    const int f = kt * 32 + ((lane >> 4) << 3) + j;
    const int n = nb * 16 + (lane & 15);
    WxF[i] = f2bf(Wx[f * H_ + n]);
  }
  if (i < H_) {
    float a[3], cc[3], qq[3];
#pragma unroll
    for (int k = 0; k < 3; ++k) {
      float s = sigma[i * 3 + k];
      cc[k] = c[i * 3 + k];
      a[k] = -LOG2E / (2.f * s * s + 1e-8f);   // mu = exp2(d*d*a)
      qq[k] = q[i * 3 + k];
    }
    gp8[i * 8 + 0] = cc[0];
    gp8[i * 8 + 1] = cc[1];
    gp8[i * 8 + 2] = cc[2];
    gp8[i * 8 + 3] = a[0];
    gp8[i * 8 + 4] = a[1];
    gp8[i * 8 + 5] = a[2];
    gp8[i * 8 + 6] = __uint_as_float((unsigned)f2bf(qq[0]) |
                                     ((unsigned)f2bf(qq[1]) << 16));
    gp8[i * 8 + 7] = __uint_as_float((unsigned)f2bf(qq[2]));
    bvec[i] = b[i];
    wcv[i] = Wc[i];
  }
}

// per-column absmax of Wh -> scales. grid 512 x 64.
__global__ void scales_kernel(const float* __restrict__ Wh,
                              float* __restrict__ scol,
                              float* __restrict__ invs) {
  const int col = blockIdx.x, lane = threadIdx.x;
  float m = 0.f;
#pragma unroll
  for (int r = 0; r < 8; ++r)
    m = fmaxf(m, fabsf(Wh[(r * 64 + lane) * H_ + col]));
#pragma unroll
  for (int d = 1; d < 64; d <<= 1) m = fmaxf(m, __shfl_xor(m, d, 64));
  if (lane == 0) {
    m = fmaxf(m, 1e-20f);
    scol[col] = m / (127.f * 127.f);
    invs[col] = 127.f / m;
  }
}

// build W2I8: i8 fragment-linear Wh. grid 256 x 256 (65536 dwords).
__global__ void w2i8_kernel(const float* __restrict__ Wh,
                            const float* __restrict__ invs,
                            int* __restrict__ W2) {
  const int d = blockIdx.x * 256 + threadIdx.x;
  const int dw = d & 3, lane = (d >> 2) & 63, nbkt = d >> 8;
  const int nb = nbkt & 31, kt = nbkt >> 5;
  const int n = nb * 16 + (lane & 15);
  const float iv = invs[n];
  int pk = 0;
#pragma unroll
  for (int jj = 0; jj < 4; ++jj) {
    const int k = kt * 64 + ((lane >> 4) << 4) + dw * 4 + jj;
    int qv = (int)rintf(Wh[k * H_ + n] * iv);
    qv = min(127, max(-127, qv));
    pk |= (qv & 255) << (8 * jj);
  }
  W2[d] = pk;
}

// xw2 = bf16(x*wts) @ bf16(Wx), stored scan-fragment-linear.
// grid (t=128, bblk64=8, nblk256=2), 256 thr.
__global__ __launch_bounds__(256, 1) void gemm1_kernel(
    const float* __restrict__ x, const float* __restrict__ wts,
    const ushort* __restrict__ WxF, ushort* __restrict__ xw2) {
  __shared__ ushort A[64 * 264];
  const int tid = threadIdx.x;
  const int lane = tid & 63, wg = tid >> 6;
  const int col16 = lane & 15, quad = lane >> 4;
  const int tt = blockIdx.x, bb = blockIdx.y, nn = blockIdx.z;

  {  // stage A: 64 rows (b=bb*64+r, t=tt) of xf=x*w -> bf16
    const int r = tid >> 2, f0 = (tid & 3) * 64;
    const float4* xp =
        (const float4*)(x + ((size_t)(bb * 64 + r) * T_ + tt) * F_ + f0);
    const float4* wp = (const float4*)(wts + f0);
#pragma unroll
    for (int j = 0; j < 16; ++j) {
      float4 xv = xp[j];
      float4 wv = wp[j];
      ushort4 o;
      o.x = f2bf(xv.x * wv.x);
      o.y = f2bf(xv.y * wv.y);
      o.z = f2bf(xv.z * wv.z);
      o.w = f2bf(xv.w * wv.w);
      *(ushort4*)&A[r * 264 + f0 + j * 4] = o;
    }
  }
  __syncthreads();

  float4v acc[16];
  const float4v zero = {0.f, 0.f, 0.f, 0.f};
#pragma unroll
  for (int i = 0; i < 16; ++i) acc[i] = zero;

#pragma unroll
  for (int kt = 0; kt < 8; ++kt) {
    short8 af = *(const short8*)&A[(wg * 16 + col16) * 264 + kt * 32 + quad * 8];
#pragma unroll
    for (int nt = 0; nt < 16; ++nt) {
      short8 bf = *(const short8*)(WxF + ((kt * 32 + nn * 16 + nt) * 64 + lane) * 8);
      acc[nt] = __builtin_amdgcn_mfma_f32_16x16x32_bf16(af, bf, acc[nt], 0, 0, 0);
    }
  }
#pragma unroll
  for (int nt = 0; nt < 16; ++nt) {
    ushort4 o;
    o.x = f2bf(acc[nt][0]);
    o.y = f2bf(acc[nt][1]);
    o.z = f2bf(acc[nt][2]);
    o.w = f2bf(acc[nt][3]);
    const size_t off =
        ((((size_t)tt * 32 + bb * 4 + wg) * 8 + nn * 4 + (nt >> 2)) * 4 +
         (nt & 3)) * 256 + (quad * 16 + col16) * 4;
    *(ushort4*)(xw2 + off) = o;
  }
}

// scan: 32 WGs x 512 thr (8 waves). Wave owns 64 h-cols (4 nt).
// Wh-i8 fully register-resident; h i8 mirror in LDS for A-frags.
__global__ __launch_bounds__(512, 2) void scan_kernel(
    const ushort* __restrict__ xw2, const int4i* __restrict__ W2,
    const float* __restrict__ gp8, const float* __restrict__ bvec,
    const float* __restrict__ wcv, const float* __restrict__ scol,
    const float* __restrict__ bc, float* __restrict__ out) {
  __shared__ int hl4[16 * 132];   // h i8 mirror: 16 rows x 528 B (132 dwords)
  __shared__ float red[8][16];
  const int tid = threadIdx.x;
  const int lane = tid & 63, w = tid >> 6;
  const int col16 = lane & 15, quad = lane >> 4;
  const int blk = blockIdx.x;

  for (int i = tid; i < 16 * 132; i += 512) hl4[i] = 0;

  // resident B-fragments: 8 kt x 4 nt x 4 VGPR = 128 VGPRs
  int4i bfr[8][4];
#pragma unroll
  for (int kt = 0; kt < 8; ++kt)
#pragma unroll
    for (int nt = 0; nt < 4; ++nt)
      bfr[kt][nt] = W2[(kt * 32 + w * 4 + nt) * 64 + lane];

  int cols[4];
  float bcol[4], scl[4];
  float c0v[4], c1v[4], c2v[4], a0v[4], a1v[4], a2v[4], q0v[4], q1v[4], q2v[4];
#pragma unroll
  for (int nt = 0; nt < 4; ++nt) {
    cols[nt] = w * 64 + nt * 16 + col16;
    bcol[nt] = bvec[cols[nt]];
    scl[nt] = scol[cols[nt]];
    float4v g0 = *(const float4v*)(gp8 + cols[nt] * 8);
    float4v g1 = *(const float4v*)(gp8 + cols[nt] * 8 + 4);
    c0v[nt] = g0[0]; c1v[nt] = g0[1]; c2v[nt] = g0[2];
    a0v[nt] = g0[3]; a1v[nt] = g1[0]; a2v[nt] = g1[1];
    unsigned p01 = __float_as_uint(g1[2]);
    unsigned p2 = __float_as_uint(g1[3]);
    q0v[nt] = bf2f(p01 & 0xffffu);
    q1v[nt] = bf2f(p01 >> 16);
    q2v[nt] = bf2f(p2 & 0xffffu);
  }
  const unsigned selA = (lane & 1) ? 0x07030501u : 0x02060004u;
  const unsigned selB = (lane & 2) ? 0x07060302u : 0x01000504u;

  float hreg[4][4];
#pragma unroll
  for (int nt = 0; nt < 4; ++nt)
#pragma unroll
    for (int rg = 0; rg < 4; ++rg) hreg[nt][rg] = 0.f;

  ushort4 xv[4], xn[4];
#pragma unroll
  for (int nt = 0; nt < 4; ++nt)
    xv[nt] = *(const ushort4*)(xw2 +
              (((size_t)0 * 32 + blk) * 32 + w * 4 + nt) * 256 + lane * 4);
  __syncthreads();

#pragma clang loop unroll(disable)
  for (int t = 0; t < T_; ++t) {
    const int tn = (t + 1) & 127;  // prefetch next step's xw (t=127 wraps, unused)
#pragma unroll
    for (int nt = 0; nt < 4; ++nt)
      xn[nt] = *(const ushort4*)(xw2 +
                (((size_t)tn * 32 + blk) * 32 + w * 4 + nt) * 256 + lane * 4);

    int4i acc[4];
    const int4i izero = {0, 0, 0, 0};
#pragma unroll
    for (int nt = 0; nt < 4; ++nt) acc[nt] = izero;
#pragma unroll
    for (int kt = 0; kt < 8; ++kt) {
      int4i a = *(const int4i*)((const char*)hl4 + col16 * 528 + kt * 64 + quad * 16);
#pragma unroll
      for (int nt = 0; nt < 4; ++nt)
        acc[nt] = __builtin_amdgcn_mfma_i32_16x16x64_i8(a, bfr[kt][nt], acc[nt], 0, 0, 0);
    }

    int pk[4];
#pragma unroll
    for (int nt = 0; nt < 4; ++nt) {
      int qb[4];
#pragma unroll
      for (int rg = 0; rg < 4; ++rg) {
        float v = bf2f((unsigned)((const ushort*)&xv[nt])[rg]);
        float z = v + bcol[nt] + (float)acc[nt][rg] * scl[nt];
        float e = fexp2(v * (2.f * LOG2E));
        float nw = 1.f - 2.f * frcp(1.f + e);          // tanh(v)
        float d0 = z - c0v[nt], d1 = z - c1v[nt], d2 = z - c2v[nt];
        float m0 = fexp2(d0 * d0 * a0v[nt]);
        float m1 = fexp2(d1 * d1 * a1v[nt]);
        float m2 = fexp2(d2 * d2 * a2v[nt]);
        float num = m0 * q0v[nt] + m1 * q1v[nt] + m2 * q2v[nt];
        float den = m0 + m1 + m2 + 1e-8f;
        float s = num * frcp(den);
        float gg = frcp(1.f + fexp2(-s * LOG2E));      // sigmoid(s)
        float h = hreg[nt][rg] + gg * (nw - hreg[nt][rg]);
        hreg[nt][rg] = h;
        qb[rg] = (int)rintf(h * 127.f);                // |h|<1 -> no clamp needed
      }
      pk[nt] = (qb[0] & 255) | ((qb[1] & 255) << 8) | ((qb[2] & 255) << 16) |
               (qb[3] << 24);
    }
    __syncthreads();  // all A-frag reads of this step done
#pragma unroll
    for (int nt = 0; nt < 4; ++nt) {
      // 4x4 byte transpose across lane groups of 4 (cols) x rg (bytes)
      int p1 = __shfl_xor(pk[nt], 1, 64);
      int A = __builtin_amdgcn_perm((unsigned)pk[nt], (unsigned)p1, selA);
      int p2 = __shfl_xor(A, 2, 64);
      int Tw = __builtin_amdgcn_perm((unsigned)A, (unsigned)p2, selB);
      hl4[(quad * 4 + (col16 & 3)) * 132 + w * 16 + nt * 4 + (col16 >> 2)] = Tw;
    }
    __syncthreads();  // h mirror updated before next step's reads
#pragma unroll
    for (int nt = 0; nt < 4; ++nt) xv[nt] = xn[nt];
  }

  // logits
  float wcl[4];
#pragma unroll
  for (int nt = 0; nt < 4; ++nt) wcl[nt] = wcv[cols[nt]];
  float part[4] = {0.f, 0.f, 0.f, 0.f};
#pragma unroll
  for (int nt = 0; nt < 4; ++nt)
#pragma unroll
    for (int rg = 0; rg < 4; ++rg) part[rg] += hreg[nt][rg] * wcl[nt];
#pragma unroll
  for (int rg = 0; rg < 4; ++rg) {
#pragma unroll
    for (int m = 1; m < 16; m <<= 1) part[rg] += __shfl_xor(part[rg], m, 64);
    if (col16 == 0) red[w][quad * 4 + rg] = part[rg];
  }
  __syncthreads();
  if (tid < 16) {
    float s = bc[0];
#pragma unroll
    for (int ww = 0; ww < 8; ++ww) s += red[ww][tid];
    out[blk * 16 + tid] = s;
  }
}

extern "C" void kernel_launch(void* const* d_in, const int* in_sizes, int n_in,
                              void* d_out, int out_size, void* d_ws, size_t ws_size,
                              hipStream_t stream) {
  const float* x     = (const float*)d_in[0];
  const float* theta = (const float*)d_in[1];
  const float* Wx    = (const float*)d_in[2];
  const float* Wh    = (const float*)d_in[3];
  const float* b     = (const float*)d_in[4];
  const float* c     = (const float*)d_in[5];
  const float* sigma = (const float*)d_in[6];
  const float* q     = (const float*)d_in[7];
  const float* Wc    = (const float*)d_in[8];
  const float* bc    = (const float*)d_in[9];
  float* out = (float*)d_out;

  ushort* xw2 = (ushort*)d_ws;
  int*    W2  = (int*)((char*)d_ws + WS_W2I8);
  ushort* WxF = (ushort*)((char*)d_ws + WS_WXF);
  float*  gp8 = (float*)((char*)d_ws + WS_GP8);
  float*  bv  = (float*)((char*)d_ws + WS_BVEC);
  float*  wcv = (float*)((char*)d_ws + WS_WCV);
  float*  scl = (float*)((char*)d_ws + WS_SCOL);
  float*  inv = (float*)((char*)d_ws + WS_INVS);
  float*  wts = (float*)((char*)d_ws + WS_WTS);

  hipLaunchKernelGGL(prep_misc, dim3(512), dim3(256), 0, stream,
                     theta, Wx, b, c, sigma, q, Wc, out + B_, WxF, gp8, bv, wcv, wts);
  hipLaunchKernelGGL(scales_kernel, dim3(512), dim3(64), 0, stream, Wh, scl, inv);
  hipLaunchKernelGGL(w2i8_kernel, dim3(256), dim3(256), 0, stream, Wh, inv, W2);
  hipLaunchKernelGGL(gemm1_kernel, dim3(128, 8, 2), dim3(256), 0, stream,
                     x, wts, WxF, xw2);
  hipLaunchKernelGGL(scan_kernel, dim3(32), dim3(512), 0, stream,
                     xw2, (const int4i*)W2, gp8, bv, wcv, scl, bc, out);
}